// Round 4
// baseline (51.451 us; speedup 1.0000x reference)
//
#include <hip/hip_runtime.h>
#include <cmath>

#define PH 7
#define PW 7
#define FH 64
#define FW 64
#define CC 512
#define SCALE 0.0625f

// ---------------------------------------------------------------------------
// Kernel 1: sort ROI indices by feature-space (start_h, start_w) so that
// consecutive sorted ROIs have overlapping windows. Combined with the
// XCD-chunked block swizzle in kernel 2, each XCD's 64 ROIs form a ~28-row
// horizontal band (~3.6 MB) that fits its private 4 MB L2.
// 512 elements, 1 block, bitonic sort in LDS. key = (sh*64+sw)<<10 | idx.
// ---------------------------------------------------------------------------
__global__ __launch_bounds__(512) void sort_rois_kernel(
        const float* __restrict__ rois, int N, int NP, int* __restrict__ perm) {
    __shared__ unsigned key[1024];
    int t = threadIdx.x;
    for (int i = t; i < NP; i += blockDim.x) {
        unsigned k = 0x7FFFFFFFu;  // sentinel > any real key
        if (i < N) {
            const float* r = rois + (size_t)i * 5;
            int sw = (int)rintf(r[1] * SCALE);
            int sh = (int)rintf(r[2] * SCALE);
            sw = min(max(sw, 0), FW - 1);
            sh = min(max(sh, 0), FH - 1);
            k = (((unsigned)(sh * FW + sw)) << 10) | (unsigned)i;
        }
        key[i] = k;
    }
    __syncthreads();
    for (int kk = 2; kk <= NP; kk <<= 1) {
        for (int j = kk >> 1; j > 0; j >>= 1) {
            for (int i = t; i < NP; i += blockDim.x) {
                int ixj = i ^ j;
                if (ixj > i) {
                    unsigned a = key[i], b = key[ixj];
                    bool up = ((i & kk) == 0);
                    if (up ? (a > b) : (a < b)) { key[i] = b; key[ixj] = a; }
                }
            }
            __syncthreads();
        }
    }
    for (int i = t; i < N; i += blockDim.x)
        perm[i] = (int)(key[i] & 0x3FFu);
}

// ---------------------------------------------------------------------------
// Kernel 2: Caffe ROI max-pool, bit-matching the XLA-compiled reference
// (bin size via reciprocal multiply: roi_h * fl32(1/7), per XLA's
// AlgebraicSimplifier — proven bit-exact in round 3).
// One bin (roi, ph, pw) = 128 consecutive threads, each owning a float4 of
// channels. Work order follows the sorted ROI permutation; the bijective
// XCD-chunk swizzle puts sorted-ROI chunk k on XCD k for L2 residency.
// ---------------------------------------------------------------------------
__global__ __launch_bounds__(256) void roi_pool_kernel(
        const float* __restrict__ feat,
        const float* __restrict__ rois,
        const int* __restrict__ perm,
        float* __restrict__ out,
        int nBins) {
    // bijective XCD-chunk swizzle: physical block p (HW: XCD = p%8) -> logical
    // work id L so that XCD k runs the contiguous chunk [k*q, (k+1)*q).
    int p = blockIdx.x;
    int nwg = gridDim.x;
    int q = nwg >> 3, rr = nwg & 7;
    int xcd = p & 7, o = p >> 3;
    int L = (xcd < rr ? xcd * (q + 1) : rr * (q + 1) + (xcd - rr) * q) + o;

    int tid = L * 256 + (int)threadIdx.x;
    int bin = tid >> 7;          // 128 threads per bin (sorted order)
    int cv  = tid & 127;         // float4 slot; channel base = cv*4
    if (bin >= nBins) return;

    int s   = bin / (PH * PW);   // sorted roi slot
    int rem = bin - s * (PH * PW);
    int ph  = rem / PW;
    int pw  = rem - ph * PW;
    int n   = perm[s];           // original roi index (output location)

    const float* r = rois + (size_t)n * 5;
    int bidx = (int)r[0];
    // jnp.round == round-half-to-even == rintf (RNE); x*0.0625 is exact
    int sw = (int)rintf(r[1] * SCALE);
    int sh = (int)rintf(r[2] * SCALE);
    int ew = (int)rintf(r[3] * SCALE);
    int eh = (int)rintf(r[4] * SCALE);

    float roi_h = fmaxf((float)(eh - sh + 1), 1.0f);
    float roi_w = fmaxf((float)(ew - sw + 1), 1.0f);
    // XLA-style reciprocal: constant-folds to fl32(1/7) = 0.14285714924f
    float bh = roi_h * (1.0f / 7.0f);
    float bw = roi_w * (1.0f / 7.0f);

    int hstart = min(max((int)floorf((float)ph * bh) + sh, 0), FH);
    int hend   = min(max((int)ceilf((float)(ph + 1) * bh) + sh, 0), FH);
    int wstart = min(max((int)floorf((float)pw * bw) + sw, 0), FW);
    int wend   = min(max((int)ceilf((float)(pw + 1) * bw) + sw, 0), FW);
    bool empty = (hend <= hstart) || (wend <= wstart);

    float4 mx = make_float4(-INFINITY, -INFINITY, -INFINITY, -INFINITY);
    const float* f = feat + (size_t)bidx * (FH * FW * CC) + (size_t)cv * 4;
    for (int h = hstart; h < hend; ++h) {
        const float* rowp = f + (size_t)h * (FW * CC);
        for (int w = wstart; w < wend; ++w) {
            const float4 v = *reinterpret_cast<const float4*>(rowp + (size_t)w * CC);
            mx.x = fmaxf(mx.x, v.x);
            mx.y = fmaxf(mx.y, v.y);
            mx.z = fmaxf(mx.z, v.z);
            mx.w = fmaxf(mx.w, v.w);
        }
    }
    if (empty) mx = make_float4(0.f, 0.f, 0.f, 0.f);

    *reinterpret_cast<float4*>(out + ((size_t)n * (PH * PW) + rem) * CC +
                               (size_t)cv * 4) = mx;
}

extern "C" void kernel_launch(void* const* d_in, const int* in_sizes, int n_in,
                              void* d_out, int out_size, void* d_ws, size_t ws_size,
                              hipStream_t stream) {
    const float* feat = (const float*)d_in[0];
    const float* rois = (const float*)d_in[1];
    float* out = (float*)d_out;
    int* perm = (int*)d_ws;

    int N = in_sizes[1] / 5;               // 512 rois
    int NP = 1;
    while (NP < N) NP <<= 1;               // next pow2 (<= 1024 assumed)
    if (NP > 1024) NP = 1024;

    sort_rois_kernel<<<1, 512, 0, stream>>>(rois, N, NP, perm);

    int nBins = N * PH * PW;               // 25088
    int totalThreads = nBins * 128;        // 128 threads per bin
    int block = 256;
    int grid = (totalThreads + block - 1) / block;
    roi_pool_kernel<<<grid, block, 0, stream>>>(feat, rois, perm, out, nBins);
}

// Round 5
// 38.438 us; speedup vs baseline: 1.3385x; 1.3385x over previous
//
#include <hip/hip_runtime.h>
#include <cmath>

#define PH 7
#define PW 7
#define FH 64
#define FW 64
#define CC 512
#define SCALE 0.0625f

// ---------------------------------------------------------------------------
// Kernel 1: order ROI indices by feature-space start row band (counting sort,
// 64 buckets, 3 barriers — replaces the 45-barrier bitonic sort that cost
// ~11 us). Combined with the XCD-chunked swizzle in kernel 2, each XCD's
// ~64 consecutive ROIs form a horizontal band that fits its private 4MB L2.
// ---------------------------------------------------------------------------
__global__ __launch_bounds__(512) void sort_rois_kernel(
        const float* __restrict__ rois, int N, int* __restrict__ perm) {
    __shared__ int base[64];
    __shared__ int cur[64];
    int t = threadIdx.x;
    if (t < 64) { base[t] = 0; cur[t] = 0; }
    __syncthreads();
    int b = -1;
    if (t < N) {
        const float* r = rois + (size_t)t * 5;
        int sh = (int)rintf(r[2] * SCALE);
        b = min(max(sh, 0), FH - 1);
        atomicAdd(&base[b], 1);
    }
    __syncthreads();
    if (t == 0) {
        int acc = 0;
        for (int i = 0; i < 64; ++i) { int c = base[i]; base[i] = acc; acc += c; }
    }
    __syncthreads();
    if (t < N) {
        int pos = base[b] + atomicAdd(&cur[b], 1);
        perm[pos] = t;
    }
}

// ---------------------------------------------------------------------------
// Kernel 2: Caffe ROI max-pool, bit-matching the XLA-compiled reference
// (bin size via reciprocal multiply roi_h * fl32(1/7) — XLA's
// AlgebraicSimplifier rewrite, proven bit-exact in round 3).
// ONE WAVE per bin: lane l owns channels [l*4, l*4+4) and [256+l*4, ...+4)
// as two float4s -> two independent coalesced 1KB loads per (h,w) cell,
// half the waves (geometry/roi loads amortized 2x vs round 4).
// ---------------------------------------------------------------------------
__global__ __launch_bounds__(256) void roi_pool_kernel(
        const float* __restrict__ feat,
        const float* __restrict__ rois,
        const int* __restrict__ perm,
        float* __restrict__ out,
        int nBins) {
    // bijective XCD-chunk swizzle: physical block p (HW: XCD = p%8) -> logical
    // work id L so that XCD k runs a contiguous chunk of sorted bins.
    int p = blockIdx.x;
    int nwg = gridDim.x;
    int q = nwg >> 3, rr = nwg & 7;
    int xcd = p & 7, o = p >> 3;
    int L = (xcd < rr ? xcd * (q + 1) : rr * (q + 1) + (xcd - rr) * q) + o;

    int tid = L * 256 + (int)threadIdx.x;
    int bin = tid >> 6;          // one 64-lane wave per bin (sorted order)
    int lane = tid & 63;
    if (bin >= nBins) return;

    int s   = bin / (PH * PW);   // sorted roi slot
    int rem = bin - s * (PH * PW);
    int ph  = rem / PW;
    int pw  = rem - ph * PW;
    int n   = perm[s];           // original roi index (output location)

    const float* r = rois + (size_t)n * 5;
    int bidx = (int)r[0];
    // jnp.round == round-half-to-even == rintf (RNE); x*0.0625 is exact
    int sw = (int)rintf(r[1] * SCALE);
    int sh = (int)rintf(r[2] * SCALE);
    int ew = (int)rintf(r[3] * SCALE);
    int eh = (int)rintf(r[4] * SCALE);

    float roi_h = fmaxf((float)(eh - sh + 1), 1.0f);
    float roi_w = fmaxf((float)(ew - sw + 1), 1.0f);
    // XLA-style reciprocal: constant-folds to fl32(1/7) = 0.14285714924f
    float bh = roi_h * (1.0f / 7.0f);
    float bw = roi_w * (1.0f / 7.0f);

    int hstart = min(max((int)floorf((float)ph * bh) + sh, 0), FH);
    int hend   = min(max((int)ceilf((float)(ph + 1) * bh) + sh, 0), FH);
    int wstart = min(max((int)floorf((float)pw * bw) + sw, 0), FW);
    int wend   = min(max((int)ceilf((float)(pw + 1) * bw) + sw, 0), FW);
    bool empty = (hend <= hstart) || (wend <= wstart);

    float4 mxA = make_float4(-INFINITY, -INFINITY, -INFINITY, -INFINITY);
    float4 mxB = mxA;
    // lane owns channels lane*4..+3 (slot A) and 256+lane*4..+3 (slot B)
    const float* f = feat + (size_t)bidx * (FH * FW * CC) + (size_t)lane * 4;
    for (int h = hstart; h < hend; ++h) {
        const float* rowp = f + (size_t)h * (FW * CC);
        for (int w = wstart; w < wend; ++w) {
            const float* cp = rowp + (size_t)w * CC;
            const float4 a = *reinterpret_cast<const float4*>(cp);
            const float4 bB = *reinterpret_cast<const float4*>(cp + 256);
            mxA.x = fmaxf(mxA.x, a.x);
            mxA.y = fmaxf(mxA.y, a.y);
            mxA.z = fmaxf(mxA.z, a.z);
            mxA.w = fmaxf(mxA.w, a.w);
            mxB.x = fmaxf(mxB.x, bB.x);
            mxB.y = fmaxf(mxB.y, bB.y);
            mxB.z = fmaxf(mxB.z, bB.z);
            mxB.w = fmaxf(mxB.w, bB.w);
        }
    }
    if (empty) {
        mxA = make_float4(0.f, 0.f, 0.f, 0.f);
        mxB = mxA;
    }

    float* op = out + ((size_t)n * (PH * PW) + rem) * CC + (size_t)lane * 4;
    *reinterpret_cast<float4*>(op) = mxA;
    *reinterpret_cast<float4*>(op + 256) = mxB;
}

extern "C" void kernel_launch(void* const* d_in, const int* in_sizes, int n_in,
                              void* d_out, int out_size, void* d_ws, size_t ws_size,
                              hipStream_t stream) {
    const float* feat = (const float*)d_in[0];
    const float* rois = (const float*)d_in[1];
    float* out = (float*)d_out;
    int* perm = (int*)d_ws;

    int N = in_sizes[1] / 5;               // 512 rois
    sort_rois_kernel<<<1, 512, 0, stream>>>(rois, N, perm);

    int nBins = N * PH * PW;               // 25088
    int totalThreads = nBins * 64;         // one wave per bin
    int block = 256;
    int grid = (totalThreads + block - 1) / block;
    roi_pool_kernel<<<grid, block, 0, stream>>>(feat, rois, perm, out, nBins);
}

// Round 6
// 33.795 us; speedup vs baseline: 1.5224x; 1.1374x over previous
//
#include <hip/hip_runtime.h>
#include <cmath>

#define PH 7
#define PW 7
#define FH 64
#define FW 64
#define CC 512
#define SCALE 0.0625f

typedef float f32x4 __attribute__((ext_vector_type(4)));

static __device__ __forceinline__ f32x4 vmax4(f32x4 a, f32x4 b) {
    f32x4 r;
    r.x = fmaxf(a.x, b.x); r.y = fmaxf(a.y, b.y);
    r.z = fmaxf(a.z, b.z); r.w = fmaxf(a.w, b.w);
    return r;
}

// ---------------------------------------------------------------------------
// Kernel 1: order ROI indices by feature-space start row (counting sort, 64
// buckets). With the XCD-chunked swizzle below, each XCD's ~64 consecutive
// sorted ROIs form a horizontal band that fits its private 4MB L2
// (proven: FETCH 112 MB -> 26 MB in round 4).
// ---------------------------------------------------------------------------
__global__ __launch_bounds__(512) void sort_rois_kernel(
        const float* __restrict__ rois, int N, int* __restrict__ perm) {
    __shared__ int base[64];
    __shared__ int cur[64];
    int t = threadIdx.x;
    if (t < 64) { base[t] = 0; cur[t] = 0; }
    __syncthreads();
    int b = -1;
    if (t < N) {
        const float* r = rois + (size_t)t * 5;
        int sh = (int)rintf(r[2] * SCALE);
        b = min(max(sh, 0), FH - 1);
        atomicAdd(&base[b], 1);
    }
    __syncthreads();
    if (t == 0) {
        int acc = 0;
        for (int i = 0; i < 64; ++i) { int c = base[i]; base[i] = acc; acc += c; }
    }
    __syncthreads();
    if (t < N) {
        int pos = base[b] + atomicAdd(&cur[b], 1);
        perm[pos] = t;
    }
}

// ---------------------------------------------------------------------------
// Kernel 2: Caffe ROI max-pool, bit-matching the XLA-compiled reference
// (bin size via reciprocal multiply roi_h * fl32(1/7) — XLA's
// AlgebraicSimplifier rewrite, proven bit-exact in round 3).
//
// One 64-lane wave per bin; lane owns channels [l*4,+4) and [256+l*4,+4).
// The (h,w) window is flattened into a cell count walked by a wave-uniform
// (SALU) pointer walker, unrolled 4 cells/iter = 8 independent dwordx4
// loads in flight (round-5 profile showed the 2-deep dynamic loop was
// latency-bound at ~250 cyc/cell). Exact tail — no duplicate reads.
// Output stores are nontemporal: 50 MB write-once stream must not evict
// the L2-resident feature band.
// ---------------------------------------------------------------------------
__global__ __launch_bounds__(256) void roi_pool_kernel(
        const float* __restrict__ feat,
        const float* __restrict__ rois,
        const int* __restrict__ perm,
        float* __restrict__ out,
        int nBins) {
    // bijective XCD-chunk swizzle (HW: XCD = blockIdx % 8)
    int p = blockIdx.x;
    int nwg = gridDim.x;
    int q = nwg >> 3, rr = nwg & 7;
    int xcd = p & 7, o = p >> 3;
    int L = (xcd < rr ? xcd * (q + 1) : rr * (q + 1) + (xcd - rr) * q) + o;

    int tid = L * 256 + (int)threadIdx.x;
    int bin = tid >> 6;          // one wave per bin (sorted order)
    int lane = tid & 63;
    if (bin >= nBins) return;

    int s   = bin / (PH * PW);   // sorted roi slot
    int rem = bin - s * (PH * PW);
    int ph  = rem / PW;
    int pw  = rem - ph * PW;
    int n   = perm[s];           // original roi index (output location)

    const float* r = rois + (size_t)n * 5;
    int bidx = (int)r[0];
    // jnp.round == round-half-to-even == rintf (RNE); x*0.0625 is exact
    int sw = (int)rintf(r[1] * SCALE);
    int sh = (int)rintf(r[2] * SCALE);
    int ew = (int)rintf(r[3] * SCALE);
    int eh = (int)rintf(r[4] * SCALE);

    float roi_h = fmaxf((float)(eh - sh + 1), 1.0f);
    float roi_w = fmaxf((float)(ew - sw + 1), 1.0f);
    // XLA-style reciprocal: constant-folds to fl32(1/7) = 0.14285714924f
    float bh = roi_h * (1.0f / 7.0f);
    float bw = roi_w * (1.0f / 7.0f);

    int hstart = min(max((int)floorf((float)ph * bh) + sh, 0), FH);
    int hend   = min(max((int)ceilf((float)(ph + 1) * bh) + sh, 0), FH);
    int wstart = min(max((int)floorf((float)pw * bw) + sw, 0), FW);
    int wend   = min(max((int)ceilf((float)(pw + 1) * bw) + sw, 0), FW);
    bool empty = (hend <= hstart) || (wend <= wstart);

    f32x4 mxA = { -INFINITY, -INFINITY, -INFINITY, -INFINITY };
    f32x4 mxB = mxA;

    if (!empty) {
        const int W = wend - wstart;
        int cells = (hend - hstart) * W;
        const float* ptr = feat + (size_t)bidx * (FH * FW * CC)
                         + (size_t)hstart * (FW * CC) + (size_t)wstart * CC
                         + (size_t)lane * 4;
        const int stepWrap = (FW - W + 1) * CC;  // last col -> next row start
        int cw = W;  // cols left in current row (incl. current ptr position)

#define ADV() do { if (--cw == 0) { ptr += stepWrap; cw = W; } else ptr += CC; } while (0)

        while (cells >= 4) {
            const float* q0 = ptr; ADV();
            const float* q1 = ptr; ADV();
            const float* q2 = ptr; ADV();
            const float* q3 = ptr; ADV();
            f32x4 a0 = *(const f32x4*)q0;        f32x4 b0 = *(const f32x4*)(q0 + 256);
            f32x4 a1 = *(const f32x4*)q1;        f32x4 b1 = *(const f32x4*)(q1 + 256);
            f32x4 a2 = *(const f32x4*)q2;        f32x4 b2 = *(const f32x4*)(q2 + 256);
            f32x4 a3 = *(const f32x4*)q3;        f32x4 b3 = *(const f32x4*)(q3 + 256);
            a0 = vmax4(a0, a1); a2 = vmax4(a2, a3);
            b0 = vmax4(b0, b1); b2 = vmax4(b2, b3);
            mxA = vmax4(mxA, vmax4(a0, a2));
            mxB = vmax4(mxB, vmax4(b0, b2));
            cells -= 4;
        }
        while (cells > 0) {
            const float* q0 = ptr; ADV();
            f32x4 a0 = *(const f32x4*)q0;
            f32x4 b0 = *(const f32x4*)(q0 + 256);
            mxA = vmax4(mxA, a0);
            mxB = vmax4(mxB, b0);
            --cells;
        }
#undef ADV
    } else {
        mxA = (f32x4){0.f, 0.f, 0.f, 0.f};
        mxB = mxA;
    }

    float* op = out + ((size_t)n * (PH * PW) + rem) * CC + (size_t)lane * 4;
    __builtin_nontemporal_store(mxA, (f32x4*)op);
    __builtin_nontemporal_store(mxB, (f32x4*)(op + 256));
}

extern "C" void kernel_launch(void* const* d_in, const int* in_sizes, int n_in,
                              void* d_out, int out_size, void* d_ws, size_t ws_size,
                              hipStream_t stream) {
    const float* feat = (const float*)d_in[0];
    const float* rois = (const float*)d_in[1];
    float* out = (float*)d_out;
    int* perm = (int*)d_ws;

    int N = in_sizes[1] / 5;               // 512 rois
    sort_rois_kernel<<<1, 512, 0, stream>>>(rois, N, perm);

    int nBins = N * PH * PW;               // 25088
    int totalThreads = nBins * 64;         // one wave per bin
    int block = 256;
    int grid = (totalThreads + block - 1) / block;
    roi_pool_kernel<<<grid, block, 0, stream>>>(feat, rois, perm, out, nBins);
}